// Round 5
// baseline (8746.549 us; speedup 1.0000x reference)
//
#include <hip/hip_runtime.h>

#define B_ 512
#define L_ 1000
#define H_ 128
#define G_ 512  // 4*H

typedef _Float16 v8h __attribute__((ext_vector_type(8)));
typedef _Float16 h2t __attribute__((ext_vector_type(2)));
typedef float v4f __attribute__((ext_vector_type(4)));

__device__ __forceinline__ float sigmoid_f(float x) {
  return __builtin_amdgcn_rcpf(1.0f + __builtin_amdgcn_exp2f(-1.4426950408889634f * x));
}
__device__ __forceinline__ float tanh_f(float x) {
  return 1.0f - 2.0f * __builtin_amdgcn_rcpf(1.0f + __builtin_amdgcn_exp2f(2.8853900817779268f * x));
}

// h storage in B-FRAGMENT ORDER: chunk (kt, quad, row) at byte offset
// kt*144 + quad*32 + row*16 holds h_row[kt*32 + quad*8 + j], j=0..7 (f16).
// C-read (per kt): quad*32 + (m15&1)*16 -> 8 distinct addrs, one per
// bank-group -> pure broadcast, zero conflicts. U-write: one dword/lane,
// max 2 lanes/bank = free (m136). kt stride 144 destaggers kt blocks.
#define FB_KT 144

#define MFMA16(a, b, c) __builtin_amdgcn_mfma_f32_16x16x32_f16((a), (b), (c), 0, 0, 0)

// ROUND-4 (= round-3 resubmit after full dependency audit; 3 infra fails).
// LAYER-STAGGERED anti-phase. 256 blocks x 1024 thr, 2 rows/block,
// N=2 MFMA sharing PRESERVED. Two segments per step, each 192 MFMA
// (48/SIMD ~= 931 cy issue) + one U hidden under it:
//   SegA(t): U1(t) [wv0,1]  || C-A: gbuf2A = A2h@h2(t-2) + [gates g,o]
//            A2i_hi@h1(t-1)                       [wv4..15, 16 MFMA each]
//   SegB(t): U2(t-1) [wv2,3] || C-B: gbuf1 = A1@h1(t); gb2L = A2i_lo@h1(t)
// U2 gates = gbuf2A + gb2L[(t-1)&1] (+bias). hb1 and gb2L parity-double-
// buffered; every producer->consumer edge crosses >=1 barrier:
//   h1(t): SegA(t) -> read SegB(t) (A1,A2i_lo) + SegA(t+1) (A2i_hi)
//   h2(t-1): SegB(t) -> read SegA(t+1) (A2h)
//   gbuf2A: SegA(t) -> U2 in SegB(t); gb2L[t&1]: SegB(t) -> U2 in SegB(t+1)
//   gbuf1: SegB(t) -> U1 in SegA(t+1)
// Rationale: round-0 profile MfmaUtil 29%/VALUBusy 15% -> ~56% of cycles
// issue NOTHING (U-segments + barrier drains park the matrix pipe). This
// schedule gives every barrier segment full MFMA issue to hide U under.
__global__ __launch_bounds__(1024) void lstm_mfma(
    const float* __restrict__ x,
    const float* __restrict__ w_ih1,
    const float* __restrict__ w_hh1,
    const float* __restrict__ b_ih1,
    const float* __restrict__ b_hh1,
    const float* __restrict__ w_ih2,
    const float* __restrict__ w_hh2,
    const float* __restrict__ b_ih2,
    const float* __restrict__ b_hh2,
    const float* __restrict__ w_lin,
    const float* __restrict__ b_lin,
    float* __restrict__ out)
{
  __shared__ __align__(16) float xlds[2][L_];        // block's 2 x-rows
  __shared__ __align__(16) float olds[2 * L_];       // staged outputs
  __shared__ __align__(16) float gbuf1[2][G_];       // [row] A1@h1 carry
  __shared__ __align__(16) float gbuf2A[2][G_];      // [row] A2h(+A2i_hi) part
  __shared__ __align__(16) float gb2L[2][2][256];    // [par][row] A2i_lo part (gates i,f)
  __shared__ __align__(16) unsigned char hb1[2][4 * FB_KT];  // [par] h1 frag-order
  __shared__ __align__(16) unsigned char hb2[4 * FB_KT];     // h2 frag-order

  const int tid  = threadIdx.x;
  const int wv   = tid >> 6;
  const int lane = tid & 63;
  const int quad = lane >> 4;
  const int m15  = lane & 15;
  const int r0   = blockIdx.x * 2;
  const int e    = 2 * lane;

  // ---- one-time staging / zero-init ----
  for (int i = tid; i < 2 * L_; i += 1024) ((float*)xlds)[i] = x[r0 * L_ + i];
  ((float*)gbuf1)[tid]  = 0.f;   // 1024 dwords each, one per thread
  ((float*)gbuf2A)[tid] = 0.f;
  ((float*)gb2L)[tid]   = 0.f;
  if (tid < 288) ((unsigned*)hb1)[tid] = 0u;   // h1(-1)=h1(-2)=0
  if (tid < 144) ((unsigned*)hb2)[tid] = 0u;   // h2(-2)=0

  // ---- role-local loop-invariant constants in registers ----
  float2 wxi = {0, 0}, wxf = {0, 0}, wxg = {0, 0}, wxo = {0, 0};
  float2 bi = {0, 0}, bf = {0, 0}, bg = {0, 0}, bo = {0, 0}, wl = {0, 0};
  float blv = 0.f;
  if (wv < 2) {  // U1 role (waves 0,1 = pair rows 0,1)
    wxi = *(const float2*)&w_ih1[e];
    wxf = *(const float2*)&w_ih1[128 + e];
    wxg = *(const float2*)&w_ih1[256 + e];
    wxo = *(const float2*)&w_ih1[384 + e];
    float2 a, b;
    a = *(const float2*)&b_ih1[e];       b = *(const float2*)&b_hh1[e];
    bi = float2{a.x + b.x, a.y + b.y};
    a = *(const float2*)&b_ih1[128 + e]; b = *(const float2*)&b_hh1[128 + e];
    bf = float2{a.x + b.x, a.y + b.y};
    a = *(const float2*)&b_ih1[256 + e]; b = *(const float2*)&b_hh1[256 + e];
    bg = float2{a.x + b.x, a.y + b.y};
    a = *(const float2*)&b_ih1[384 + e]; b = *(const float2*)&b_hh1[384 + e];
    bo = float2{a.x + b.x, a.y + b.y};
  } else if (wv < 4) {  // U2 role (waves 2,3 = pair rows 0,1)
    float2 a, b;
    a = *(const float2*)&b_ih2[e];       b = *(const float2*)&b_hh2[e];
    bi = float2{a.x + b.x, a.y + b.y};
    a = *(const float2*)&b_ih2[128 + e]; b = *(const float2*)&b_hh2[128 + e];
    bf = float2{a.x + b.x, a.y + b.y};
    a = *(const float2*)&b_ih2[256 + e]; b = *(const float2*)&b_hh2[256 + e];
    bg = float2{a.x + b.x, a.y + b.y};
    a = *(const float2*)&b_ih2[384 + e]; b = *(const float2*)&b_hh2[384 + e];
    bo = float2{a.x + b.x, a.y + b.y};
    wl = *(const float2*)&w_lin[e];
    blv = b_lin[0];
  }

  // ---- C-wave fragments: WA = SegA slots, WB = SegB slots (4 each) ----
  // cw<8:  WA = {A2h[16+2cw], A2h[17+2cw], A2i[16+2cw], A2i[17+2cw]}
  //        WB = {A1[2cw], A1[2cw+1], A2i[2cw], A2i[2cw+1]}
  // cw>=8: WA = A2h[4(cw-8)+s]; WB = A1[16+4(cw-8)+s]
  const int cw = wv - 4;
  v8h WA[4][4], WB[4][4];
  if (wv >= 4) {
    const float* srcA[4]; int mtA[4];
    const float* srcB[4]; int mtB[4];
    if (cw < 8) {
      srcA[0] = w_hh2; mtA[0] = 16 + 2 * cw;
      srcA[1] = w_hh2; mtA[1] = 17 + 2 * cw;
      srcA[2] = w_ih2; mtA[2] = 16 + 2 * cw;
      srcA[3] = w_ih2; mtA[3] = 17 + 2 * cw;
      srcB[0] = w_hh1; mtB[0] = 2 * cw;
      srcB[1] = w_hh1; mtB[1] = 2 * cw + 1;
      srcB[2] = w_ih2; mtB[2] = 2 * cw;
      srcB[3] = w_ih2; mtB[3] = 2 * cw + 1;
    } else {
#pragma unroll
      for (int s = 0; s < 4; ++s) {
        srcA[s] = w_hh2; mtA[s] = 4 * (cw - 8) + s;
        srcB[s] = w_hh1; mtB[s] = 16 + 4 * (cw - 8) + s;
      }
    }
#pragma unroll
    for (int s = 0; s < 4; ++s) {
      const int ga = (mtA[s] * 16 + m15) * H_;
      const int gb = (mtB[s] * 16 + m15) * H_;
#pragma unroll
      for (int kt = 0; kt < 4; ++kt) {
        const int koff = kt * 32 + quad * 8;
        float4 a = *(const float4*)(srcA[s] + ga + koff);
        float4 b = *(const float4*)(srcA[s] + ga + koff + 4);
        WA[s][kt] = v8h{(_Float16)a.x, (_Float16)a.y, (_Float16)a.z, (_Float16)a.w,
                        (_Float16)b.x, (_Float16)b.y, (_Float16)b.z, (_Float16)b.w};
        a = *(const float4*)(srcB[s] + gb + koff);
        b = *(const float4*)(srcB[s] + gb + koff + 4);
        WB[s][kt] = v8h{(_Float16)a.x, (_Float16)a.y, (_Float16)a.z, (_Float16)a.w,
                        (_Float16)b.x, (_Float16)b.y, (_Float16)b.z, (_Float16)b.w};
      }
    }
  }

  float c1x = 0.f, c1y = 0.f;  // layer-1 cell state (waves 0,1)
  float c2x = 0.f, c2y = 0.f;  // layer-2 cell state (waves 2,3)

  // U write offset: k=2*lane -> byte kt*144 + quad'*32 + (l&3)*4
  const int hwo = (lane >> 4) * FB_KT + ((lane >> 2) & 3) * 32 + (lane & 3) * 4;
  const int roff = quad * 32 + (m15 & 1) * 16;

  __syncthreads();

  for (int t = 0; t <= L_; ++t) {
    // ================= Segment A: U1(t) || C-A =================
    if (wv < 2) {
      if (t < L_) {
        const int row = wv;
        const float xv = xlds[row][t];
        const float* g1 = gbuf1[row];
        float2 gi = *(const float2*)&g1[e];
        float2 gf = *(const float2*)&g1[128 + e];
        float2 gg = *(const float2*)&g1[256 + e];
        float2 go = *(const float2*)&g1[384 + e];
        float i0 = sigmoid_f(gi.x + wxi.x * xv + bi.x);
        float i1 = sigmoid_f(gi.y + wxi.y * xv + bi.y);
        float f0 = sigmoid_f(gf.x + wxf.x * xv + bf.x);
        float f1 = sigmoid_f(gf.y + wxf.y * xv + bf.y);
        float g0 = tanh_f(gg.x + wxg.x * xv + bg.x);
        float g1v = tanh_f(gg.y + wxg.y * xv + bg.y);
        float o0 = sigmoid_f(go.x + wxo.x * xv + bo.x);
        float o1 = sigmoid_f(go.y + wxo.y * xv + bo.y);
        c1x = f0 * c1x + i0 * g0;
        c1y = f1 * c1y + i1 * g1v;
        h2t hp = h2t{(_Float16)(o0 * tanh_f(c1x)), (_Float16)(o1 * tanh_f(c1y))};
        *(unsigned*)(&hb1[t & 1][0] + row * 16 + hwo) = __builtin_bit_cast(unsigned, hp);
      }
    } else if (wv >= 4) {
      // C-A: gbuf2A = A2h@h2(t-2) (+ A2i_hi@h1(t-1) on rows 256..511)
      v4f a0 = {0,0,0,0}, a1 = {0,0,0,0}, a2 = {0,0,0,0}, a3 = {0,0,0,0};
      const unsigned char* b2p = hb2;
      const unsigned char* b1p = &hb1[(t + 1) & 1][0];  // (t-1)&1
      __builtin_amdgcn_s_setprio(1);
      if (cw < 8) {
#pragma unroll
        for (int kt = 0; kt < 4; ++kt) {
          v8h b2 = *(const v8h*)(b2p + kt * FB_KT + roff);
          v8h b1 = *(const v8h*)(b1p + kt * FB_KT + roff);
          a0 = MFMA16(WA[0][kt], b2, a0);
          a1 = MFMA16(WA[1][kt], b2, a1);
          a0 = MFMA16(WA[2][kt], b1, a0);
          a1 = MFMA16(WA[3][kt], b1, a1);
        }
        __builtin_amdgcn_s_setprio(0);
        if (m15 < 2) {
          *(v4f*)&gbuf2A[m15][(16 + 2 * cw) * 16 + quad * 4] = a0;
          *(v4f*)&gbuf2A[m15][(17 + 2 * cw) * 16 + quad * 4] = a1;
        }
      } else {
#pragma unroll
        for (int kt = 0; kt < 4; ++kt) {
          v8h b2 = *(const v8h*)(b2p + kt * FB_KT + roff);
          a0 = MFMA16(WA[0][kt], b2, a0);
          a1 = MFMA16(WA[1][kt], b2, a1);
          a2 = MFMA16(WA[2][kt], b2, a2);
          a3 = MFMA16(WA[3][kt], b2, a3);
        }
        __builtin_amdgcn_s_setprio(0);
        if (m15 < 2) {
          *(v4f*)&gbuf2A[m15][(4 * (cw - 8) + 0) * 16 + quad * 4] = a0;
          *(v4f*)&gbuf2A[m15][(4 * (cw - 8) + 1) * 16 + quad * 4] = a1;
          *(v4f*)&gbuf2A[m15][(4 * (cw - 8) + 2) * 16 + quad * 4] = a2;
          *(v4f*)&gbuf2A[m15][(4 * (cw - 8) + 3) * 16 + quad * 4] = a3;
        }
      }
    }
    __syncthreads();

    // ================= Segment B: U2(t-1) || C-B =================
    if (wv >= 4) {
      if (t < L_) {
        // C-B: gbuf1 = A1@h1(t); gb2L[t&1] = A2i_lo@h1(t)
        v4f a0 = {0,0,0,0}, a1 = {0,0,0,0}, a2 = {0,0,0,0}, a3 = {0,0,0,0};
        const unsigned char* b1p = &hb1[t & 1][0];
        __builtin_amdgcn_s_setprio(1);
#pragma unroll
        for (int kt = 0; kt < 4; ++kt) {
          v8h b1 = *(const v8h*)(b1p + kt * FB_KT + roff);
          a0 = MFMA16(WB[0][kt], b1, a0);
          a1 = MFMA16(WB[1][kt], b1, a1);
          a2 = MFMA16(WB[2][kt], b1, a2);
          a3 = MFMA16(WB[3][kt], b1, a3);
        }
        __builtin_amdgcn_s_setprio(0);
        if (cw < 8) {
          if (m15 < 2) {
            *(v4f*)&gbuf1[m15][(2 * cw) * 16 + quad * 4]     = a0;
            *(v4f*)&gbuf1[m15][(2 * cw + 1) * 16 + quad * 4] = a1;
            *(v4f*)&gb2L[t & 1][m15][(2 * cw) * 16 + quad * 4]     = a2;
            *(v4f*)&gb2L[t & 1][m15][(2 * cw + 1) * 16 + quad * 4] = a3;
          }
        } else {
          if (m15 < 2) {
            *(v4f*)&gbuf1[m15][(16 + 4 * (cw - 8) + 0) * 16 + quad * 4] = a0;
            *(v4f*)&gbuf1[m15][(16 + 4 * (cw - 8) + 1) * 16 + quad * 4] = a1;
            *(v4f*)&gbuf1[m15][(16 + 4 * (cw - 8) + 2) * 16 + quad * 4] = a2;
            *(v4f*)&gbuf1[m15][(16 + 4 * (cw - 8) + 3) * 16 + quad * 4] = a3;
          }
        }
      }
    } else if (wv >= 2) {
      if (t > 0) {
        const int row = wv - 2;
        const float* gA = gbuf2A[row];
        const float* gL = gb2L[(t + 1) & 1][row];  // (t-1)&1
        float2 giA = *(const float2*)&gA[e];
        float2 giL = *(const float2*)&gL[e];
        float2 gfA = *(const float2*)&gA[128 + e];
        float2 gfL = *(const float2*)&gL[128 + e];
        float2 gg = *(const float2*)&gA[256 + e];
        float2 go = *(const float2*)&gA[384 + e];
        float i0 = sigmoid_f(giA.x + giL.x + bi.x);
        float i1 = sigmoid_f(giA.y + giL.y + bi.y);
        float f0 = sigmoid_f(gfA.x + gfL.x + bf.x);
        float f1 = sigmoid_f(gfA.y + gfL.y + bf.y);
        float g0 = tanh_f(gg.x + bg.x);
        float g1v = tanh_f(gg.y + bg.y);
        float o0 = sigmoid_f(go.x + bo.x);
        float o1 = sigmoid_f(go.y + bo.y);
        c2x = f0 * c2x + i0 * g0;
        c2y = f1 * c2y + i1 * g1v;
        float h0 = o0 * tanh_f(c2x);
        float h1 = o1 * tanh_f(c2y);
        h2t hp = h2t{(_Float16)h0, (_Float16)h1};
        *(unsigned*)(hb2 + row * 16 + hwo) = __builtin_bit_cast(unsigned, hp);
        float p2 = h0 * wl.x + h1 * wl.y;
#pragma unroll
        for (int s = 1; s < 64; s <<= 1) p2 += __shfl_xor(p2, s, 64);
        if (lane == 0) olds[row * L_ + (t - 1)] = p2 + blv;
      }
    }
    __syncthreads();
  }

  // ---- one-shot coalesced flush of staged outputs ----
  for (int i = tid; i < 2 * L_; i += 1024) out[r0 * L_ + i] = olds[i];
}

extern "C" void kernel_launch(void* const* d_in, const int* in_sizes, int n_in,
                              void* d_out, int out_size, void* d_ws, size_t ws_size,
                              hipStream_t stream) {
  const float* x     = (const float*)d_in[0];
  const float* w_ih1 = (const float*)d_in[1];
  const float* w_hh1 = (const float*)d_in[2];
  const float* b_ih1 = (const float*)d_in[3];
  const float* b_hh1 = (const float*)d_in[4];
  const float* w_ih2 = (const float*)d_in[5];
  const float* w_hh2 = (const float*)d_in[6];
  const float* b_ih2 = (const float*)d_in[7];
  const float* b_hh2 = (const float*)d_in[8];
  const float* w_lin = (const float*)d_in[9];
  const float* b_lin = (const float*)d_in[10];

  lstm_mfma<<<B_ / 2, 1024, 0, stream>>>(
      x, w_ih1, w_hh1, b_ih1, b_hh1, w_ih2, w_hh2, b_ih2, b_hh2,
      w_lin, b_lin, (float*)d_out);
}

// Round 7
// 3060.974 us; speedup vs baseline: 2.8574x; 2.8574x over previous
//
#include <hip/hip_runtime.h>

#define B_ 512
#define L_ 1000
#define H_ 128
#define G_ 512  // 4*H

typedef _Float16 v8h __attribute__((ext_vector_type(8)));
typedef _Float16 h2t __attribute__((ext_vector_type(2)));
typedef float v4f __attribute__((ext_vector_type(4)));

__device__ __forceinline__ float sigmoid_f(float x) {
  return __builtin_amdgcn_rcpf(1.0f + __builtin_amdgcn_exp2f(-1.4426950408889634f * x));
}
__device__ __forceinline__ float tanh_f(float x) {
  return 1.0f - 2.0f * __builtin_amdgcn_rcpf(1.0f + __builtin_amdgcn_exp2f(2.8853900817779268f * x));
}

// h storage in B-FRAGMENT ORDER: chunk (kt, quad, row) at byte offset
// kt*144 + quad*32 + row*16 holds h_row[kt*32 + quad*8 + j], j=0..7 (f16).
// C-read (per kt): quad*32 + (m15&1)*16 -> 8 distinct addrs, one per
// bank-group -> pure broadcast, zero conflicts. U-write: one dword/lane,
// max 2 lanes/bank = free (m136). kt stride 144 destaggers kt blocks.
#define FB_KT 144

#define MFMA16(a, b, c) __builtin_amdgcn_mfma_f32_16x16x32_f16((a), (b), (c), 0, 0, 0)

// ROUND-6 (= round-5 resubmit after second audit; 4th infra fail).
// Layer-staggered anti-phase schedule on round-0's verified no-spill
// register layout. Round-3 post-mortem: FETCH_SIZE 28.5 GB/dispatch at
// MfmaUtil 7% = weight fragments spilled to scratch (128 frag dwords + 32
// acc concentrated on 12 waves) and re-fetched every step. Fix: ALL 16
// waves hold round-0's fragment set (mtiles 2w,2w+1 of A1,A2i,A2h = 96
// dwords), U-constants in LDS, no pointer arrays, uniform fragment init.
// Schedule (2 segments/step, every segment MFMA-saturated, U hidden):
//   SegA(t): U1(t) [wv0,1]   || all: gbuf2 = A2h@h2(t-2) + A2i@h1(t-1)  (16 MFMA)
//   SegB(t): U2(t-1) [wv2,3] || all: gbuf1 = A1@h1(t)                   (8 MFMA)
// Dependencies (all cross >=1 barrier):
//   h1(t): SegA(t)[hb1[t&1]] -> SegB(t) (A1) + SegA(t+1) (A2i, parity t&1)
//   h2(t-1): SegB(t)[hb2] -> SegA(t+1) (A2h); overwritten SegB(t+1) after read
//   gbuf2: SegA(t) -> U2(t-1) in SegB(t);  gbuf1: SegB(t) -> U1(t+1) in SegA(t+1)
// U2(tau) gates = A2i@h1(tau) + A2h@h2(tau-1) + bias  (tau = t-1)  == reference.
__global__ __launch_bounds__(1024) void lstm_mfma(
    const float* __restrict__ x,
    const float* __restrict__ w_ih1,
    const float* __restrict__ w_hh1,
    const float* __restrict__ b_ih1,
    const float* __restrict__ b_hh1,
    const float* __restrict__ w_ih2,
    const float* __restrict__ w_hh2,
    const float* __restrict__ b_ih2,
    const float* __restrict__ b_hh2,
    const float* __restrict__ w_lin,
    const float* __restrict__ b_lin,
    float* __restrict__ out)
{
  __shared__ __align__(16) float xlds[2][L_];        // block's 2 x-rows
  __shared__ __align__(16) float olds[2 * L_];       // staged outputs
  __shared__ __align__(16) float gbuf1[2][G_];       // [row] A1@h1 carry
  __shared__ __align__(16) float gbuf2[2][G_];       // [row] A2i@h1 + A2h@h2
  __shared__ __align__(16) unsigned char hb1[2][4 * FB_KT];  // [parity] h1 frag-order
  __shared__ __align__(16) unsigned char hb2[4 * FB_KT];     // h2 frag-order
  __shared__ __align__(16) float wxb[G_];            // w_ih1 column (LDS: protects regs)
  __shared__ __align__(16) float bbb1[G_];           // b_ih1+b_hh1
  __shared__ __align__(16) float bbb2[G_];           // b_ih2+b_hh2
  __shared__ __align__(16) float wlb[H_];            // w_lin row

  const int tid  = threadIdx.x;
  const int wv   = tid >> 6;
  const int lane = tid & 63;
  const int quad = lane >> 4;
  const int m15  = lane & 15;
  const int r0   = blockIdx.x * 2;
  const int e    = 2 * lane;

  // ---- one-time staging / zero-init ----
  for (int i = tid; i < 2 * L_; i += 1024) ((float*)xlds)[i] = x[r0 * L_ + i];
  ((float*)gbuf1)[tid] = 0.f;                  // 1024 dwords = whole gbuf1
  if (tid < G_) {
    wxb[tid]  = w_ih1[tid];
    bbb1[tid] = b_ih1[tid] + b_hh1[tid];
    bbb2[tid] = b_ih2[tid] + b_hh2[tid];
  }
  if (tid < H_) wlb[tid] = w_lin[tid];
  if (tid < 288) ((unsigned*)hb1)[tid] = 0u;   // h1(-1) = 0 (both parities)
  if (tid < 144) ((unsigned*)hb2)[tid] = 0u;   // h2(-1) = h2(-2) = 0
  const float blv = b_lin[0];

  // ---- per-wave fragments: mtiles 2wv, 2wv+1 of A1,A2i,A2h (96 dwords) ----
  v8h A1f[2][4], A2if[2][4], A2hf[2][4];
#pragma unroll
  for (int mt = 0; mt < 2; ++mt) {
    const int grow = ((2 * wv + mt) * 16 + m15) * H_;
#pragma unroll
    for (int kt = 0; kt < 4; ++kt) {
      const int koff = kt * 32 + quad * 8;
      float4 a, b;
      a = *(const float4*)(w_hh1 + grow + koff);
      b = *(const float4*)(w_hh1 + grow + koff + 4);
      A1f[mt][kt] = v8h{(_Float16)a.x, (_Float16)a.y, (_Float16)a.z, (_Float16)a.w,
                        (_Float16)b.x, (_Float16)b.y, (_Float16)b.z, (_Float16)b.w};
      a = *(const float4*)(w_ih2 + grow + koff);
      b = *(const float4*)(w_ih2 + grow + koff + 4);
      A2if[mt][kt] = v8h{(_Float16)a.x, (_Float16)a.y, (_Float16)a.z, (_Float16)a.w,
                         (_Float16)b.x, (_Float16)b.y, (_Float16)b.z, (_Float16)b.w};
      a = *(const float4*)(w_hh2 + grow + koff);
      b = *(const float4*)(w_hh2 + grow + koff + 4);
      A2hf[mt][kt] = v8h{(_Float16)a.x, (_Float16)a.y, (_Float16)a.z, (_Float16)a.w,
                         (_Float16)b.x, (_Float16)b.y, (_Float16)b.z, (_Float16)b.w};
    }
  }

  float c1x = 0.f, c1y = 0.f;  // layer-1 cell state (waves 0,1; row = wv)
  float c2x = 0.f, c2y = 0.f;  // layer-2 cell state (waves 2,3; row = wv-2)

  // U write offset: elements 2*lane,2*lane+1 -> byte kt*144 + quad'*32 + (l&3)*4
  const int hwo = (lane >> 4) * FB_KT + ((lane >> 2) & 3) * 32 + (lane & 3) * 4;
  const int roff = quad * 32 + (m15 & 1) * 16;

  __syncthreads();

  for (int t = 0; t <= L_; ++t) {
    // ================= Segment A: U1(t) || gbuf2 = A2h@h2(t-2)+A2i@h1(t-1) =====
    if (wv < 2 && t < L_) {
      const int row = wv;
      const float xv = xlds[row][t];
      const float* g1 = gbuf1[row];
      float2 gi = *(const float2*)&g1[e];
      float2 gf = *(const float2*)&g1[128 + e];
      float2 gg = *(const float2*)&g1[256 + e];
      float2 go = *(const float2*)&g1[384 + e];
      float2 wxi = *(const float2*)&wxb[e],       bi = *(const float2*)&bbb1[e];
      float2 wxf = *(const float2*)&wxb[128 + e], bf = *(const float2*)&bbb1[128 + e];
      float2 wxg = *(const float2*)&wxb[256 + e], bg = *(const float2*)&bbb1[256 + e];
      float2 wxo = *(const float2*)&wxb[384 + e], bo = *(const float2*)&bbb1[384 + e];
      float i0 = sigmoid_f(gi.x + wxi.x * xv + bi.x);
      float i1 = sigmoid_f(gi.y + wxi.y * xv + bi.y);
      float f0 = sigmoid_f(gf.x + wxf.x * xv + bf.x);
      float f1 = sigmoid_f(gf.y + wxf.y * xv + bf.y);
      float g0 = tanh_f(gg.x + wxg.x * xv + bg.x);
      float g1v = tanh_f(gg.y + wxg.y * xv + bg.y);
      float o0 = sigmoid_f(go.x + wxo.x * xv + bo.x);
      float o1 = sigmoid_f(go.y + wxo.y * xv + bo.y);
      c1x = f0 * c1x + i0 * g0;
      c1y = f1 * c1y + i1 * g1v;
      h2t hp = h2t{(_Float16)(o0 * tanh_f(c1x)), (_Float16)(o1 * tanh_f(c1y))};
      *(unsigned*)(&hb1[t & 1][0] + row * 16 + hwo) = __builtin_bit_cast(unsigned, hp);
    }
    {  // C-A: all 16 waves, 16 MFMA each
      v4f a0 = {0, 0, 0, 0}, a1 = {0, 0, 0, 0};
      const unsigned char* b2p = hb2;
      const unsigned char* b1p = &hb1[(t + 1) & 1][0];  // h1(t-1)
      __builtin_amdgcn_s_setprio(1);
#pragma unroll
      for (int kt = 0; kt < 4; ++kt) {
        v8h b2 = *(const v8h*)(b2p + kt * FB_KT + roff);
        v8h b1 = *(const v8h*)(b1p + kt * FB_KT + roff);
        a0 = MFMA16(A2hf[0][kt], b2, a0);
        a1 = MFMA16(A2hf[1][kt], b2, a1);
        a0 = MFMA16(A2if[0][kt], b1, a0);
        a1 = MFMA16(A2if[1][kt], b1, a1);
      }
      __builtin_amdgcn_s_setprio(0);
      if (m15 < 2) {  // col = m15 = batch row; rows = gate indices
        *(v4f*)&gbuf2[m15][(2 * wv) * 16 + quad * 4]     = a0;
        *(v4f*)&gbuf2[m15][(2 * wv + 1) * 16 + quad * 4] = a1;
      }
    }
    __syncthreads();

    // ================= Segment B: U2(t-1) || gbuf1 = A1@h1(t) =================
    if (wv >= 2 && wv < 4 && t > 0) {
      const int row = wv - 2;
      const float* g2 = gbuf2[row];
      float2 gi = *(const float2*)&g2[e];
      float2 gf = *(const float2*)&g2[128 + e];
      float2 gg = *(const float2*)&g2[256 + e];
      float2 go = *(const float2*)&g2[384 + e];
      float2 bi = *(const float2*)&bbb2[e];
      float2 bf = *(const float2*)&bbb2[128 + e];
      float2 bg = *(const float2*)&bbb2[256 + e];
      float2 bo = *(const float2*)&bbb2[384 + e];
      float i0 = sigmoid_f(gi.x + bi.x);
      float i1 = sigmoid_f(gi.y + bi.y);
      float f0 = sigmoid_f(gf.x + bf.x);
      float f1 = sigmoid_f(gf.y + bf.y);
      float g0 = tanh_f(gg.x + bg.x);
      float g1v = tanh_f(gg.y + bg.y);
      float o0 = sigmoid_f(go.x + bo.x);
      float o1 = sigmoid_f(go.y + bo.y);
      c2x = f0 * c2x + i0 * g0;
      c2y = f1 * c2y + i1 * g1v;
      float h0 = o0 * tanh_f(c2x);
      float h1 = o1 * tanh_f(c2y);
      h2t hp = h2t{(_Float16)h0, (_Float16)h1};
      *(unsigned*)(hb2 + row * 16 + hwo) = __builtin_bit_cast(unsigned, hp);
      float2 wlv = *(const float2*)&wlb[e];
      float p2 = h0 * wlv.x + h1 * wlv.y;
#pragma unroll
      for (int s = 1; s < 64; s <<= 1) p2 += __shfl_xor(p2, s, 64);
      if (lane == 0) olds[row * L_ + (t - 1)] = p2 + blv;
    }
    if (t < L_) {  // C-B: all 16 waves, 8 MFMA each
      v4f a0 = {0, 0, 0, 0}, a1 = {0, 0, 0, 0};
      const unsigned char* b1p = &hb1[t & 1][0];  // h1(t)
      __builtin_amdgcn_s_setprio(1);
#pragma unroll
      for (int kt = 0; kt < 4; ++kt) {
        v8h b1 = *(const v8h*)(b1p + kt * FB_KT + roff);
        a0 = MFMA16(A1f[0][kt], b1, a0);
        a1 = MFMA16(A1f[1][kt], b1, a1);
      }
      __builtin_amdgcn_s_setprio(0);
      if (m15 < 2) {
        *(v4f*)&gbuf1[m15][(2 * wv) * 16 + quad * 4]     = a0;
        *(v4f*)&gbuf1[m15][(2 * wv + 1) * 16 + quad * 4] = a1;
      }
    }
    __syncthreads();
  }

  // ---- one-shot coalesced flush of staged outputs ----
  for (int i = tid; i < 2 * L_; i += 1024) out[r0 * L_ + i] = olds[i];
}

extern "C" void kernel_launch(void* const* d_in, const int* in_sizes, int n_in,
                              void* d_out, int out_size, void* d_ws, size_t ws_size,
                              hipStream_t stream) {
  const float* x     = (const float*)d_in[0];
  const float* w_ih1 = (const float*)d_in[1];
  const float* w_hh1 = (const float*)d_in[2];
  const float* b_ih1 = (const float*)d_in[3];
  const float* b_hh1 = (const float*)d_in[4];
  const float* w_ih2 = (const float*)d_in[5];
  const float* w_hh2 = (const float*)d_in[6];
  const float* b_ih2 = (const float*)d_in[7];
  const float* b_hh2 = (const float*)d_in[8];
  const float* w_lin = (const float*)d_in[9];
  const float* b_lin = (const float*)d_in[10];

  lstm_mfma<<<B_ / 2, 1024, 0, stream>>>(
      x, w_ih1, w_hh1, b_ih1, b_hh1, w_ih2, w_hh2, b_ih2, b_hh2,
      w_lin, b_lin, (float*)d_out);
}

// Round 9
// 1603.948 us; speedup vs baseline: 5.4531x; 1.9084x over previous
//
#include <hip/hip_runtime.h>

#define B_ 512
#define L_ 1000
#define H_ 128
#define G_ 512  // 4*H

typedef _Float16 v8h __attribute__((ext_vector_type(8)));
typedef _Float16 h2t __attribute__((ext_vector_type(2)));
typedef float v4f __attribute__((ext_vector_type(4)));

__device__ __forceinline__ float sigmoid_f(float x) {
  return __builtin_amdgcn_rcpf(1.0f + __builtin_amdgcn_exp2f(-1.4426950408889634f * x));
}
__device__ __forceinline__ float tanh_f(float x) {
  return 1.0f - 2.0f * __builtin_amdgcn_rcpf(1.0f + __builtin_amdgcn_exp2f(2.8853900817779268f * x));
}

// h storage in B-FRAGMENT ORDER: chunk (kt, quad, row) at byte offset
// kt*144 + quad*32 + row*16 holds h_row[kt*32 + quad*8 + j], j=0..7 (f16).
// C-read (per kt): quad*32 + (m15&1)*16 -> 8 distinct addrs, one per
// bank-group -> pure broadcast, zero conflicts. U-write: one dword/lane,
// max 2 lanes/bank = free (m136). kt stride 144 destaggers kt blocks.
#define FB_KT 144

#define MFMA16(a, b, c) __builtin_amdgcn_mfma_f32_16x16x32_f16((a), (b), (c), 0, 0, 0)

// ROUND-8 (= ROUND-7 LEAN-8 resubmit; 5th infra fail, re-audited clean).
// Round-0 vs round-6 A/B isolated the real cost: per-C-burst overhead
// (redundant LDS b128 broadcast storm + lgkm wait + barrier drain), which
// scales with WAVE COUNT, not MFMA issue (round-6's 2 bursts/step =
// +2000cy/step, MfmaUtil 29->21%). Fix: round-0's EXACT dataflow (one U-seg +
// one C-seg per step, same buffers/parity/U-code) on 8 waves instead of 16:
// 512 thr/block, wave w owns mtiles 4w..4w+3 of A1,A2i,A2h (48 MFMA, 192
// frag dwords; fits <=256 regs/wave at 2 waves/SIMD). Halves the ds_read
// storm (64 vs 128 instrs) and barrier cost; per-SIMD MFMA issue unchanged
// (2 waves x 48 = 96 = 466cy). No pointer arrays / no lambdas (round-3's
// spill trigger). Schedule per step t (2 barriers):
//   SegU: U1(t) [wv0-1] || U2(t-1) [wv2-3]     (waves 4-7 idle)
//   SegC: all 8 waves: gbuf2 = A2i@h1(t)+A2h@h2(t-1); gbuf1 = A1@h1(t)
// Deps (each crosses 1 barrier): hb1/hb2: SegU(t)->SegC(t), next write
// SegU(t+1); gbuf1/gbuf2: SegC(t)->SegU(t+1).
__global__ __launch_bounds__(512, 2) void lstm_mfma(
    const float* __restrict__ x,
    const float* __restrict__ w_ih1,
    const float* __restrict__ w_hh1,
    const float* __restrict__ b_ih1,
    const float* __restrict__ b_hh1,
    const float* __restrict__ w_ih2,
    const float* __restrict__ w_hh2,
    const float* __restrict__ b_ih2,
    const float* __restrict__ b_hh2,
    const float* __restrict__ w_lin,
    const float* __restrict__ b_lin,
    float* __restrict__ out)
{
  __shared__ __align__(16) float xlds[2][L_];        // block's 2 x-rows
  __shared__ __align__(16) float olds[2 * L_];       // staged outputs
  __shared__ __align__(16) float gbuf1[2][G_];       // [row] A1@h1 carry
  __shared__ __align__(16) float gbuf2[2][G_];       // [row] gates2 raw
  __shared__ __align__(16) unsigned char hb1[4 * FB_KT];  // h1(t), frag order
  __shared__ __align__(16) unsigned char hb2[4 * FB_KT];  // h2(t-1), frag order
  __shared__ __align__(16) float wxb[G_];            // w_ih1 column
  __shared__ __align__(16) float bbb1[G_];           // b_ih1+b_hh1
  __shared__ __align__(16) float bbb2[G_];           // b_ih2+b_hh2
  __shared__ __align__(16) float wlb[H_];            // w_lin row

  const int tid  = threadIdx.x;        // 0..511
  const int wv   = tid >> 6;           // 0..7
  const int lane = tid & 63;
  const int quad = lane >> 4;
  const int m15  = lane & 15;
  const int r0   = blockIdx.x * 2;
  const int e    = 2 * lane;

  // ---- one-time staging / zero-init (512 threads) ----
  for (int i = tid; i < 2 * L_; i += 512) ((float*)xlds)[i] = x[r0 * L_ + i];
  ((float*)gbuf1)[tid]       = 0.f;    // 1024 dwords total
  ((float*)gbuf1)[tid + 512] = 0.f;
  wxb[tid]  = w_ih1[tid];              // tid spans exactly G_
  bbb1[tid] = b_ih1[tid] + b_hh1[tid];
  bbb2[tid] = b_ih2[tid] + b_hh2[tid];
  if (tid < H_) wlb[tid] = w_lin[tid];
  if (tid < 144) {                      // 4*FB_KT/4 dwords each
    ((unsigned*)hb1)[tid] = 0u;
    ((unsigned*)hb2)[tid] = 0u;         // h2(-1) = 0
  }
  const float blv = b_lin[0];

  // ---- per-wave fragments: mtiles 4wv..4wv+3 of A1,A2i,A2h (192 dwords) ----
  v8h A1f[4][4], A2if[4][4], A2hf[4][4];
#pragma unroll
  for (int mt = 0; mt < 4; ++mt) {
    const int grow = ((4 * wv + mt) * 16 + m15) * H_;
#pragma unroll
    for (int kt = 0; kt < 4; ++kt) {
      const int koff = kt * 32 + quad * 8;
      float4 a, b;
      a = *(const float4*)(w_hh1 + grow + koff);
      b = *(const float4*)(w_hh1 + grow + koff + 4);
      A1f[mt][kt] = v8h{(_Float16)a.x, (_Float16)a.y, (_Float16)a.z, (_Float16)a.w,
                        (_Float16)b.x, (_Float16)b.y, (_Float16)b.z, (_Float16)b.w};
      a = *(const float4*)(w_ih2 + grow + koff);
      b = *(const float4*)(w_ih2 + grow + koff + 4);
      A2if[mt][kt] = v8h{(_Float16)a.x, (_Float16)a.y, (_Float16)a.z, (_Float16)a.w,
                         (_Float16)b.x, (_Float16)b.y, (_Float16)b.z, (_Float16)b.w};
      a = *(const float4*)(w_hh2 + grow + koff);
      b = *(const float4*)(w_hh2 + grow + koff + 4);
      A2hf[mt][kt] = v8h{(_Float16)a.x, (_Float16)a.y, (_Float16)a.z, (_Float16)a.w,
                         (_Float16)b.x, (_Float16)b.y, (_Float16)b.z, (_Float16)b.w};
    }
  }

  float c1x = 0.f, c1y = 0.f;  // layer-1 cell state (waves 0,1; row = wv)
  float c2x = 0.f, c2y = 0.f;  // layer-2 cell state (waves 2,3; row = wv-2)

  // U write offset: elements 2*lane,2*lane+1 -> byte kt*144 + quad'*32 + (l&3)*4
  const int hwo = (lane >> 4) * FB_KT + ((lane >> 2) & 3) * 32 + (lane & 3) * 4;
  const int roff = quad * 32 + (m15 & 1) * 16;

  __syncthreads();

  for (int t = 0; t <= L_; ++t) {
    // ================= SegU: U1(t) [wv0-1] || U2(t-1) [wv2-3] =================
    if (tid < 128) {
      if (t < L_) {
        const int row = tid >> 6;
        const float xv = xlds[row][t];
        const float* g1 = gbuf1[row];
        float2 gi = *(const float2*)&g1[e];
        float2 gf = *(const float2*)&g1[128 + e];
        float2 gg = *(const float2*)&g1[256 + e];
        float2 go = *(const float2*)&g1[384 + e];
        float2 wxi = *(const float2*)&wxb[e],       bi = *(const float2*)&bbb1[e];
        float2 wxf = *(const float2*)&wxb[128 + e], bf = *(const float2*)&bbb1[128 + e];
        float2 wxg = *(const float2*)&wxb[256 + e], bg = *(const float2*)&bbb1[256 + e];
        float2 wxo = *(const float2*)&wxb[384 + e], bo = *(const float2*)&bbb1[384 + e];
        float i0 = sigmoid_f(gi.x + wxi.x * xv + bi.x);
        float i1 = sigmoid_f(gi.y + wxi.y * xv + bi.y);
        float f0 = sigmoid_f(gf.x + wxf.x * xv + bf.x);
        float f1 = sigmoid_f(gf.y + wxf.y * xv + bf.y);
        float g0 = tanh_f(gg.x + wxg.x * xv + bg.x);
        float g1v = tanh_f(gg.y + wxg.y * xv + bg.y);
        float o0 = sigmoid_f(go.x + wxo.x * xv + bo.x);
        float o1 = sigmoid_f(go.y + wxo.y * xv + bo.y);
        c1x = f0 * c1x + i0 * g0;
        c1y = f1 * c1y + i1 * g1v;
        h2t hp = h2t{(_Float16)(o0 * tanh_f(c1x)), (_Float16)(o1 * tanh_f(c1y))};
        *(unsigned*)(hb1 + row * 16 + hwo) = __builtin_bit_cast(unsigned, hp);
      }
    } else if (tid < 256) {
      if (t > 0) {
        const int row = (tid >> 6) & 1;
        const float* g2 = gbuf2[row];
        float2 gi = *(const float2*)&g2[e];
        float2 gf = *(const float2*)&g2[128 + e];
        float2 gg = *(const float2*)&g2[256 + e];
        float2 go = *(const float2*)&g2[384 + e];
        float2 bi = *(const float2*)&bbb2[e];
        float2 bf = *(const float2*)&bbb2[128 + e];
        float2 bg = *(const float2*)&bbb2[256 + e];
        float2 bo = *(const float2*)&bbb2[384 + e];
        float i0 = sigmoid_f(gi.x + bi.x);
        float i1 = sigmoid_f(gi.y + bi.y);
        float f0 = sigmoid_f(gf.x + bf.x);
        float f1 = sigmoid_f(gf.y + bf.y);
        float g0 = tanh_f(gg.x + bg.x);
        float g1v = tanh_f(gg.y + bg.y);
        float o0 = sigmoid_f(go.x + bo.x);
        float o1 = sigmoid_f(go.y + bo.y);
        c2x = f0 * c2x + i0 * g0;
        c2y = f1 * c2y + i1 * g1v;
        float h0 = o0 * tanh_f(c2x);
        float h1 = o1 * tanh_f(c2y);
        h2t hp = h2t{(_Float16)h0, (_Float16)h1};
        *(unsigned*)(hb2 + row * 16 + hwo) = __builtin_bit_cast(unsigned, hp);
        float2 wlv = *(const float2*)&wlb[e];
        float p2 = h0 * wlv.x + h1 * wlv.y;
#pragma unroll
        for (int s = 1; s < 64; s <<= 1) p2 += __shfl_xor(p2, s, 64);
        if (lane == 0) olds[row * L_ + (t - 1)] = p2 + blv;
      }
    }
    __syncthreads();

    // ================= SegC: all 8 waves, 48 MFMA each =================
    if (t < L_) {
      v4f a2[4], a1[4];
#pragma unroll
      for (int m = 0; m < 4; ++m) { a2[m] = v4f{0, 0, 0, 0}; a1[m] = v4f{0, 0, 0, 0}; }
      __builtin_amdgcn_s_setprio(1);
#pragma unroll
      for (int kt = 0; kt < 4; ++kt) {
        v8h b1 = *(const v8h*)(hb1 + kt * FB_KT + roff);  // h1(t)
        v8h b2 = *(const v8h*)(hb2 + kt * FB_KT + roff);  // h2(t-1)
#pragma unroll
        for (int m = 0; m < 4; ++m) {
          a2[m] = MFMA16(A2if[m][kt], b1, a2[m]);
          a2[m] = MFMA16(A2hf[m][kt], b2, a2[m]);
          a1[m] = MFMA16(A1f[m][kt],  b1, a1[m]);
        }
      }
      __builtin_amdgcn_s_setprio(0);
      if (m15 < 2) {  // col = m15 = batch row; rows = gate indices
#pragma unroll
        for (int m = 0; m < 4; ++m) {
          *(v4f*)&gbuf2[m15][(4 * wv + m) * 16 + quad * 4] = a2[m];
          *(v4f*)&gbuf1[m15][(4 * wv + m) * 16 + quad * 4] = a1[m];
        }
      }
    }
    __syncthreads();
  }

  // ---- one-shot coalesced flush of staged outputs ----
  for (int i = tid; i < 2 * L_; i += 512) out[r0 * L_ + i] = olds[i];
}

extern "C" void kernel_launch(void* const* d_in, const int* in_sizes, int n_in,
                              void* d_out, int out_size, void* d_ws, size_t ws_size,
                              hipStream_t stream) {
  const float* x     = (const float*)d_in[0];
  const float* w_ih1 = (const float*)d_in[1];
  const float* w_hh1 = (const float*)d_in[2];
  const float* b_ih1 = (const float*)d_in[3];
  const float* b_hh1 = (const float*)d_in[4];
  const float* w_ih2 = (const float*)d_in[5];
  const float* w_hh2 = (const float*)d_in[6];
  const float* b_ih2 = (const float*)d_in[7];
  const float* b_hh2 = (const float*)d_in[8];
  const float* w_lin = (const float*)d_in[9];
  const float* b_lin = (const float*)d_in[10];

  lstm_mfma<<<B_ / 2, 512, 0, stream>>>(
      x, w_ih1, w_hh1, b_ih1, b_hh1, w_ih2, w_hh2, b_ih2, b_hh2,
      w_lin, b_lin, (float*)d_out);
}